// Round 30
// baseline (746.722 us; speedup 1.0000x reference)
//
#include <hip/hip_runtime.h>
#include <hip/hip_bf16.h>
#include <hip/hip_cooperative_groups.h>

#define NN 8192
#define NE 131072

namespace cg = cooperative_groups;

typedef __attribute__((ext_vector_type(8))) short bfrag;
typedef __attribute__((ext_vector_type(4))) float f32x4;

__device__ __forceinline__ float sigmoidf_(float x){ return 1.0f/(1.0f + __expf(-x)); }

// ---------------- utility ----------------
__global__ void k_copyf(const float* __restrict__ in, float* __restrict__ out, int n){
  int i = blockIdx.x*blockDim.x + threadIdx.x;
  if (i < n) out[i] = in[i];
}

// ---------------- CSR build (verified) ----------------
__global__ void k_zero(int* __restrict__ p, int n){
  int i = blockIdx.x*blockDim.x + threadIdx.x;
  if (i < n) p[i] = 0;
}
__global__ void k_hist(const int* __restrict__ sidx, int* __restrict__ counts){
  int e = blockIdx.x*blockDim.x + threadIdx.x;
  if (e < NE) atomicAdd(&counts[sidx[e]], 1);
}
__global__ void k_scan(const int* __restrict__ counts, int* __restrict__ row_start,
                       int* __restrict__ cursor){
  __shared__ int part[1024];
  int t = threadIdx.x;
  int base = t*8;
  int local[8]; int s = 0;
  #pragma unroll
  for (int i=0;i<8;i++){ s += counts[base+i]; local[i] = s; }
  part[t] = s;
  __syncthreads();
  for (int off=1; off<1024; off<<=1){
    int v = (t >= off) ? part[t-off] : 0;
    __syncthreads();
    part[t] += v;
    __syncthreads();
  }
  int excl = (t==0) ? 0 : part[t-1];
  int run = excl;
  #pragma unroll
  for (int i=0;i<8;i++){
    cursor[base+i] = run;
    run = excl + local[i];
    row_start[base+i+1] = run;
  }
  if (t==0) row_start[0] = 0;
}
__global__ void k_scatter(const int* __restrict__ sidx, const int* __restrict__ gidx,
                          const float* __restrict__ val, int* __restrict__ cursor,
                          int* __restrict__ gath_s, float* __restrict__ val_s){
  int e = blockIdx.x*blockDim.x + threadIdx.x;
  if (e < NE){
    int r = sidx[e];
    int pos = atomicAdd(&cursor[r], 1);
    gath_s[pos] = gidx[e];
    val_s[pos] = val[e];
  }
}

// ---------------- SpMM (verified) ----------------
__global__ void k_spmm(const int* __restrict__ row_start, const int* __restrict__ gath_s,
                       const float* __restrict__ val_s, const float* __restrict__ S,
                       float* __restrict__ H, int D){
  int r = blockIdx.x;
  int s0 = row_start[r], s1 = row_start[r+1];
  for (int c = threadIdx.x; c < D; c += blockDim.x){
    float acc = 0.f;
    for (int j = s0; j < s1; ++j)
      acc = fmaf(val_s[j], S[(size_t)gath_s[j]*D + c], acc);
    H[(size_t)r*D + c] = acc;
  }
}

// ---------------- SpMM + bf16 hi/lo split epilogue (for x_hat, D=512) ----------------
__global__ void k_spmm_split(const int* __restrict__ row_start, const int* __restrict__ gath_s,
                             const float* __restrict__ val_s, const float* __restrict__ S,
                             float* __restrict__ H, short* __restrict__ hi,
                             short* __restrict__ lo, int D){
  int r = blockIdx.x;
  int s0 = row_start[r], s1 = row_start[r+1];
  for (int c = threadIdx.x; c < D; c += blockDim.x){
    float acc = 0.f;
    for (int j = s0; j < s1; ++j)
      acc = fmaf(val_s[j], S[(size_t)gath_s[j]*D + c], acc);
    size_t idx = (size_t)r*D + c;
    H[idx] = acc;
    __hip_bfloat16 h = __float2bfloat16(acc);
    float hf = __bfloat162float(h);
    __hip_bfloat16 l = __float2bfloat16(acc - hf);
    hi[idx] = *(short*)&h;
    lo[idx] = *(short*)&l;
  }
}

// ---------------- fp32 GEMM 64-tile: C = act(A @ B). ACT: 0=none 1=tanh (verified) ----------------
template<int ACT>
__global__ __launch_bounds__(256) void k_gemm64(const float* __restrict__ A,
                                                const float* __restrict__ B,
                                                float* __restrict__ C,
                                                int M, int N, int K){
  __shared__ float As[16][65];
  __shared__ float Bs[16][65];
  int bm = blockIdx.x, bn = blockIdx.y;
  int t = threadIdx.x;
  int tx = t & 15, ty = t >> 4;
  const int rA = t >> 2, kvA = t & 3;
  const int krB = t >> 4, nvB = t & 15;
  float acc[4][4] = {};
  for (int k0 = 0; k0 < K; k0 += 16){
    float4 av = *(const float4*)(A + (size_t)(bm*64 + rA)*K + (k0 + kvA*4));
    float4 bv = *(const float4*)(B + (size_t)(k0 + krB)*N + (bn*64 + nvB*4));
    As[kvA*4+0][rA] = av.x; As[kvA*4+1][rA] = av.y;
    As[kvA*4+2][rA] = av.z; As[kvA*4+3][rA] = av.w;
    Bs[krB][nvB*4+0] = bv.x; Bs[krB][nvB*4+1] = bv.y;
    Bs[krB][nvB*4+2] = bv.z; Bs[krB][nvB*4+3] = bv.w;
    __syncthreads();
    #pragma unroll
    for (int k=0;k<16;k++){
      float a[4], b[4];
      #pragma unroll
      for (int i=0;i<4;i++) a[i] = As[k][ty*4+i];
      #pragma unroll
      for (int j=0;j<4;j++) b[j] = Bs[k][tx*4+j];
      #pragma unroll
      for (int i=0;i<4;i++)
        #pragma unroll
        for (int j=0;j<4;j++)
          acc[i][j] = fmaf(a[i], b[j], acc[i][j]);
    }
    __syncthreads();
  }
  #pragma unroll
  for (int i=0;i<4;i++){
    int rowg = bm*64 + ty*4 + i;
    float4 v;
    v.x = acc[i][0]; v.y = acc[i][1]; v.z = acc[i][2]; v.w = acc[i][3];
    if (ACT == 1){
      v.x = tanhf(v.x); v.y = tanhf(v.y); v.z = tanhf(v.z); v.w = tanhf(v.w);
    }
    *(float4*)(C + (size_t)rowg*N + (bn*64 + tx*4)) = v;
  }
}

// ---------------- NEW: fp32 GEMM 128x128 tile (for N >= 128) ----------------
template<int ACT>
__global__ __launch_bounds__(256) void k_gemm128(const float* __restrict__ A,
                                                 const float* __restrict__ B,
                                                 float* __restrict__ C,
                                                 int M, int N, int K){
  __shared__ float As[16][128];
  __shared__ float Bs[16][128];
  int bm = blockIdx.x, bn = blockIdx.y;
  int t = threadIdx.x;
  int tx = t & 15, ty = t >> 4;
  int rL = t >> 1, sL = (t & 1) << 3;     // A loader: row 0..127, k-seg 0/8
  int krB = t >> 4, cqB = (t & 15) << 3;  // B loader: k-row 0..15, col-base (x8)
  float acc[4][4][4] = {};
  for (int k0 = 0; k0 < K; k0 += 16){
    const float* pa = A + (size_t)(bm*128 + rL)*K + (k0 + sL);
    float4 a0 = *(const float4*)pa, a1 = *(const float4*)(pa+4);
    As[sL+0][rL]=a0.x; As[sL+1][rL]=a0.y; As[sL+2][rL]=a0.z; As[sL+3][rL]=a0.w;
    As[sL+4][rL]=a1.x; As[sL+5][rL]=a1.y; As[sL+6][rL]=a1.z; As[sL+7][rL]=a1.w;
    const float* pb = B + (size_t)(k0 + krB)*N + bn*128 + cqB;
    float4 b0 = *(const float4*)pb, b1 = *(const float4*)(pb+4);
    *(float4*)&Bs[krB][cqB]   = b0;
    *(float4*)&Bs[krB][cqB+4] = b1;
    __syncthreads();
    #pragma unroll
    for (int k=0;k<16;k++){
      float4 a0v = *(const float4*)&As[k][ty*4];
      float4 a1v = *(const float4*)&As[k][64 + ty*4];
      float4 b0v = *(const float4*)&Bs[k][tx*4];
      float4 b1v = *(const float4*)&Bs[k][64 + tx*4];
      float ar[8] = {a0v.x,a0v.y,a0v.z,a0v.w, a1v.x,a1v.y,a1v.z,a1v.w};
      float br[8] = {b0v.x,b0v.y,b0v.z,b0v.w, b1v.x,b1v.y,b1v.z,b1v.w};
      #pragma unroll
      for (int sub=0; sub<4; ++sub){
        int ai = (sub>>1)<<2, bj = (sub&1)<<2;
        #pragma unroll
        for (int i=0;i<4;i++)
          #pragma unroll
          for (int j=0;j<4;j++)
            acc[sub][i][j] = fmaf(ar[ai+i], br[bj+j], acc[sub][i][j]);
      }
    }
    __syncthreads();
  }
  #pragma unroll
  for (int sub=0; sub<4; ++sub){
    int rb = bm*128 + ((sub>>1)<<6) + ty*4;
    int cb = bn*128 + ((sub&1)<<6) + tx*4;
    #pragma unroll
    for (int i=0;i<4;i++){
      float4 v;
      v.x = acc[sub][i][0]; v.y = acc[sub][i][1];
      v.z = acc[sub][i][2]; v.w = acc[sub][i][3];
      if (ACT == 1){
        v.x = tanhf(v.x); v.y = tanhf(v.y); v.z = tanhf(v.z); v.w = tanhf(v.w);
      }
      *(float4*)(C + (size_t)(rb+i)*N + cb) = v;
    }
  }
}

// ---------------- split-bf16 MFMA SYRK with sigmoid, symmetric (verified) ----------------
__global__ __launch_bounds__(256) void k_syrk_mfma_sig(const short* __restrict__ Hi,
                                                       const short* __restrict__ Lo,
                                                       int K, float* __restrict__ out){
  int bm = blockIdx.x, bn = blockIdx.y;
  if (bn > bm) return;
  __shared__ short LA[2][128][40];
  __shared__ short LB[2][128][40];
  int t = threadIdx.x;
  int wid = t >> 6, lane = t & 63;
  int r0 = lane & 15;
  int kg = lane >> 4;
  f32x4 acc[2][8];
  #pragma unroll
  for (int i=0;i<2;i++)
    #pragma unroll
    for (int j=0;j<8;j++) acc[i][j] = (f32x4){0.f,0.f,0.f,0.f};

  int tr = t >> 1, th = t & 1;
  const short* gAh = Hi + (size_t)(bm*128 + tr)*K + th*16;
  const short* gAl = Lo + (size_t)(bm*128 + tr)*K + th*16;
  const short* gBh = Hi + (size_t)(bn*128 + tr)*K + th*16;
  const short* gBl = Lo + (size_t)(bn*128 + tr)*K + th*16;

  for (int k0 = 0; k0 < K; k0 += 32){
    *(int4*)&LA[0][tr][th*16] = *(const int4*)(gAh + k0);
    *(int4*)&LA[0][tr][th*16+8] = *(const int4*)(gAh + k0 + 8);
    *(int4*)&LA[1][tr][th*16] = *(const int4*)(gAl + k0);
    *(int4*)&LA[1][tr][th*16+8] = *(const int4*)(gAl + k0 + 8);
    *(int4*)&LB[0][tr][th*16] = *(const int4*)(gBh + k0);
    *(int4*)&LB[0][tr][th*16+8] = *(const int4*)(gBh + k0 + 8);
    *(int4*)&LB[1][tr][th*16] = *(const int4*)(gBl + k0);
    *(int4*)&LB[1][tr][th*16+8] = *(const int4*)(gBl + k0 + 8);
    __syncthreads();
    int ar0 = wid*32 + r0, ar1 = wid*32 + 16 + r0;
    bfrag ah0 = *(bfrag*)&LA[0][ar0][kg*8];
    bfrag ah1 = *(bfrag*)&LA[0][ar1][kg*8];
    bfrag al0 = *(bfrag*)&LA[1][ar0][kg*8];
    bfrag al1 = *(bfrag*)&LA[1][ar1][kg*8];
    #pragma unroll
    for (int j=0;j<8;j++){
      int bc = j*16 + r0;
      bfrag bh = *(bfrag*)&LB[0][bc][kg*8];
      bfrag bl = *(bfrag*)&LB[1][bc][kg*8];
      acc[0][j] = __builtin_amdgcn_mfma_f32_16x16x32_bf16(ah0, bh, acc[0][j], 0,0,0);
      acc[0][j] = __builtin_amdgcn_mfma_f32_16x16x32_bf16(ah0, bl, acc[0][j], 0,0,0);
      acc[0][j] = __builtin_amdgcn_mfma_f32_16x16x32_bf16(al0, bh, acc[0][j], 0,0,0);
      acc[1][j] = __builtin_amdgcn_mfma_f32_16x16x32_bf16(ah1, bh, acc[1][j], 0,0,0);
      acc[1][j] = __builtin_amdgcn_mfma_f32_16x16x32_bf16(ah1, bl, acc[1][j], 0,0,0);
      acc[1][j] = __builtin_amdgcn_mfma_f32_16x16x32_bf16(al1, bh, acc[1][j], 0,0,0);
    }
    __syncthreads();
  }
  #pragma unroll
  for (int i=0;i<2;i++){
    int rb = bm*128 + wid*32 + i*16 + kg*4;
    #pragma unroll
    for (int j=0;j<8;j++){
      int cb = bn*128 + j*16 + r0;
      #pragma unroll
      for (int v=0;v<4;v++){
        float s = sigmoidf_(acc[i][j][v]);
        out[(size_t)(rb+v)*NN + cb] = s;
        if (bm != bn) out[(size_t)cb*NN + (rb+v)] = s;
      }
    }
  }
}

// ---------------- fp32 symmetric 128-tile SYRK (verified; z_adj ws-path) ----------------
__global__ __launch_bounds__(256) void k_syrk128_sig(const float* __restrict__ X, int K,
                                                     float* __restrict__ out){
  int bm = blockIdx.x, bn = blockIdx.y;
  if (bn > bm) return;
  __shared__ float As[16][128];
  __shared__ float Bs[16][128];
  int t = threadIdx.x;
  int tx = t & 15, ty = t >> 4;
  int rL = t >> 1, sL = (t & 1) << 3;
  float acc[4][4][4] = {};
  for (int k0 = 0; k0 < K; k0 += 16){
    const float* pa = X + (size_t)(bm*128 + rL)*K + (k0 + sL);
    const float* pb = X + (size_t)(bn*128 + rL)*K + (k0 + sL);
    float4 a0 = *(const float4*)pa, a1 = *(const float4*)(pa+4);
    float4 b0 = *(const float4*)pb, b1 = *(const float4*)(pb+4);
    As[sL+0][rL]=a0.x; As[sL+1][rL]=a0.y; As[sL+2][rL]=a0.z; As[sL+3][rL]=a0.w;
    As[sL+4][rL]=a1.x; As[sL+5][rL]=a1.y; As[sL+6][rL]=a1.z; As[sL+7][rL]=a1.w;
    Bs[sL+0][rL]=b0.x; Bs[sL+1][rL]=b0.y; Bs[sL+2][rL]=b0.z; Bs[sL+3][rL]=b0.w;
    Bs[sL+4][rL]=b1.x; Bs[sL+5][rL]=b1.y; Bs[sL+6][rL]=b1.z; Bs[sL+7][rL]=b1.w;
    __syncthreads();
    #pragma unroll
    for (int k=0;k<16;k++){
      float4 a0v = *(const float4*)&As[k][ty*4];
      float4 a1v = *(const float4*)&As[k][64 + ty*4];
      float4 b0v = *(const float4*)&Bs[k][tx*4];
      float4 b1v = *(const float4*)&Bs[k][64 + tx*4];
      float ar[8] = {a0v.x,a0v.y,a0v.z,a0v.w, a1v.x,a1v.y,a1v.z,a1v.w};
      float br[8] = {b0v.x,b0v.y,b0v.z,b0v.w, b1v.x,b1v.y,b1v.z,b1v.w};
      #pragma unroll
      for (int sub=0; sub<4; ++sub){
        int ai = (sub>>1)<<2, bj = (sub&1)<<2;
        #pragma unroll
        for (int i=0;i<4;i++)
          #pragma unroll
          for (int j=0;j<4;j++)
            acc[sub][i][j] = fmaf(ar[ai+i], br[bj+j], acc[sub][i][j]);
      }
    }
    __syncthreads();
  }
  #pragma unroll
  for (int sub=0; sub<4; ++sub)
    #pragma unroll
    for (int i=0;i<4;i++)
      #pragma unroll
      for (int j=0;j<4;j++)
        acc[sub][i][j] = sigmoidf_(acc[sub][i][j]);
  #pragma unroll
  for (int sub=0; sub<4; ++sub){
    int rb = bm*128 + ((sub>>1)<<6) + ty*4;
    int cb = bn*128 + ((sub&1)<<6) + tx*4;
    #pragma unroll
    for (int i=0;i<4;i++){
      float4 v;
      v.x = acc[sub][i][0]; v.y = acc[sub][i][1];
      v.z = acc[sub][i][2]; v.w = acc[sub][i][3];
      *(float4*)(out + (size_t)(rb+i)*NN + cb) = v;
    }
    if (bm != bn){
      #pragma unroll
      for (int j=0;j<4;j++){
        float4 w;
        w.x = acc[sub][0][j]; w.y = acc[sub][1][j];
        w.z = acc[sub][2][j]; w.w = acc[sub][3][j];
        *(float4*)(out + (size_t)(cb+j)*NN + rb) = w;
      }
    }
  }
}

// ---------------- old 64-tile sigmoid SYRK (verified; no-ws z_adj path) ----------------
__global__ __launch_bounds__(256) void k_syrk_sig(const float* __restrict__ X, int K,
                                                  float* __restrict__ out, int bm0){
  __shared__ float As[16][65];
  __shared__ float Bs[16][65];
  int bm = blockIdx.x + bm0, bn = blockIdx.y;
  int t = threadIdx.x;
  int tx = t & 15, ty = t >> 4;
  const int rL = t >> 2, kvL = t & 3;
  float acc[4][4] = {};
  for (int k0 = 0; k0 < K; k0 += 16){
    float4 av = *(const float4*)(X + (size_t)(bm*64 + rL)*K + (k0 + kvL*4));
    float4 bv = *(const float4*)(X + (size_t)(bn*64 + rL)*K + (k0 + kvL*4));
    As[kvL*4+0][rL] = av.x; As[kvL*4+1][rL] = av.y;
    As[kvL*4+2][rL] = av.z; As[kvL*4+3][rL] = av.w;
    Bs[kvL*4+0][rL] = bv.x; Bs[kvL*4+1][rL] = bv.y;
    Bs[kvL*4+2][rL] = bv.z; Bs[kvL*4+3][rL] = bv.w;
    __syncthreads();
    #pragma unroll
    for (int k=0;k<16;k++){
      float a[4], b[4];
      #pragma unroll
      for (int i=0;i<4;i++) a[i] = As[k][ty*4+i];
      #pragma unroll
      for (int j=0;j<4;j++) b[j] = Bs[k][tx*4+j];
      #pragma unroll
      for (int i=0;i<4;i++)
        #pragma unroll
        for (int j=0;j<4;j++)
          acc[i][j] = fmaf(a[i], b[j], acc[i][j]);
    }
    __syncthreads();
  }
  #pragma unroll
  for (int i=0;i<4;i++){
    int rowg = bm*64 + ty*4 + i;
    float4 v;
    v.x = sigmoidf_(acc[i][0]); v.y = sigmoidf_(acc[i][1]);
    v.z = sigmoidf_(acc[i][2]); v.w = sigmoidf_(acc[i][3]);
    *(float4*)(out + (size_t)rowg*NN + (bn*64 + tx*4)) = v;
  }
}

// ---------------- cooperative fallback: z_adj rows 0..63 (verified) ----------------
__global__ __launch_bounds__(256) void k_zcoop(const float* __restrict__ Z,
                                               float* __restrict__ zadj){
  __shared__ float Za[64][65];
  __shared__ float Zb[64][65];
  int bm = blockIdx.x;
  int bn = blockIdx.y;
  int t = threadIdx.x;
  #pragma unroll
  for (int q=0;q<4;q++){
    int lin = q*256 + t;
    int r  = lin >> 4;
    int kq = lin & 15;
    float4 a = *(const float4*)(Z + (size_t)(bm*64 + r)*64 + kq*4);
    float4 b = *(const float4*)(Z + (size_t)(bn*64 + r)*64 + kq*4);
    Za[kq*4+0][r] = a.x; Za[kq*4+1][r] = a.y; Za[kq*4+2][r] = a.z; Za[kq*4+3][r] = a.w;
    Zb[kq*4+0][r] = b.x; Zb[kq*4+1][r] = b.y; Zb[kq*4+2][r] = b.z; Zb[kq*4+3][r] = b.w;
  }
  cg::this_grid().sync();
  int tx = t & 15, ty = t >> 4;
  float acc[4][4] = {};
  #pragma unroll 16
  for (int k=0;k<64;k++){
    float a[4], b[4];
    #pragma unroll
    for (int i=0;i<4;i++) a[i] = Za[k][ty*4+i];
    #pragma unroll
    for (int j=0;j<4;j++) b[j] = Zb[k][tx*4+j];
    #pragma unroll
    for (int i=0;i<4;i++)
      #pragma unroll
      for (int j=0;j<4;j++)
        acc[i][j] = fmaf(a[i], b[j], acc[i][j]);
  }
  #pragma unroll
  for (int i=0;i<4;i++){
    int rowg = bm*64 + ty*4 + i;
    float4 v;
    v.x = sigmoidf_(acc[i][0]); v.y = sigmoidf_(acc[i][1]);
    v.z = sigmoidf_(acc[i][2]); v.w = sigmoidf_(acc[i][3]);
    *(float4*)(zadj + (size_t)rowg*NN + (bn*64 + tx*4)) = v;
  }
}

extern "C" void kernel_launch(void* const* d_in, const int* in_sizes, int n_in,
                              void* d_out, int out_size, void* d_ws, size_t ws_size,
                              hipStream_t stream){
  (void)in_sizes; (void)n_in; (void)out_size;
  const float* x       = (const float*)d_in[0];
  const int*   adj_row = (const int*)d_in[1];
  const int*   adj_col = (const int*)d_in[2];
  const float* adj_val = (const float*)d_in[3];
  const float* W1 = (const float*)d_in[4];
  const float* W2 = (const float*)d_in[5];
  const float* W3 = (const float*)d_in[6];
  const float* W4 = (const float*)d_in[7];
  const float* W5 = (const float*)d_in[8];
  const float* W6 = (const float*)d_in[9];

  float* out      = (float*)d_out;
  float* zx_out   = out;                       // [8192,64]    f32 (pass)
  float* zadj_out = out + 524288;              // [8192,8192]  f32 (pass)
  float* xhat_out = out + 67633152;            // [8192,512]   f32 (pass)
  float* adj_out  = out + 71827456;            // [8192,8192]  f32 (pass)

  const size_t MiB = (size_t)1 << 20;
  char* R1 = (char*)zadj_out;
  float* Z   = (float*)(R1 + 0*MiB);
  float* S   = (float*)(R1 + 4*MiB);
  float* H   = (float*)(R1 + 24*MiB);
  short* XHi = (short*)(R1 + 34*MiB);          // [8192][512] bf16 hi
  short* XLo = (short*)(R1 + 43*MiB);          // [8192][512] bf16 lo
  int*   counts    = (int*)(R1 + 52*MiB);
  int*   row_start = counts + NN;
  int*   cursor    = row_start + NN + 1;
  int*   gath_s    = cursor + NN;
  float* val_s     = (float*)(gath_s + NE);
  float* Zws = (float*)d_ws;
  const bool use_ws = (ws_size >= 2*MiB);

  // ---- CSR build (VERIFIED) ----
  k_zero<<<NN/256, 256, 0, stream>>>(counts, NN);
  k_hist<<<NE/256, 256, 0, stream>>>(adj_row, counts);
  k_scan<<<1, 1024, 0, stream>>>(counts, row_start, cursor);
  k_scatter<<<NE/256, 256, 0, stream>>>(adj_row, adj_col, adj_val, cursor, gath_s, val_s);

  // ---- encoder: tanh, tanh, linear pre-agg (128-tile gemms where N>=128) ----
  k_gemm128<1><<<dim3(64,2), 256, 0, stream>>>(x, W1, S, NN, 256, 512);
  k_spmm<<<NN, 256, 0, stream>>>(row_start, gath_s, val_s, S, H, 256);
  k_gemm128<1><<<dim3(64,1), 256, 0, stream>>>(H, W2, S, NN, 128, 256);
  k_spmm<<<NN, 128, 0, stream>>>(row_start, gath_s, val_s, S, H, 128);
  k_gemm64<0><<<dim3(128,1), 256, 0, stream>>>(H, W3, S, NN, 64, 128);
  k_spmm<<<NN, 64, 0, stream>>>(row_start, gath_s, val_s, S, Z, 64);
  if (use_ws) k_copyf<<<2048, 256, 0, stream>>>(Z, Zws, NN*64);
  k_copyf<<<2048, 256, 0, stream>>>(Z, zx_out, NN*64);           // z_x FINAL

  // ---- decoder: tanh x3 pre-agg; last spmm writes xhat + bf16 split fused ----
  k_gemm128<1><<<dim3(64,1), 256, 0, stream>>>(Z, W4, S, NN, 128, 64);
  k_spmm<<<NN, 128, 0, stream>>>(row_start, gath_s, val_s, S, H, 128);
  k_gemm128<1><<<dim3(64,2), 256, 0, stream>>>(H, W5, S, NN, 256, 128);
  k_spmm<<<NN, 256, 0, stream>>>(row_start, gath_s, val_s, S, H, 256);
  k_gemm128<1><<<dim3(64,4), 256, 0, stream>>>(H, W6, S, NN, 512, 256);
  k_spmm_split<<<NN, 256, 0, stream>>>(row_start, gath_s, val_s, S, xhat_out,
                                       XHi, XLo, 512);           // x_hat FINAL + split

  // ---- adj_hat: split-bf16 MFMA syrk (verified) ----
  k_syrk_mfma_sig<<<dim3(64,64), 256, 0, stream>>>(XHi, XLo, 512, adj_out);   // adj FINAL

  // ---- z_adj LAST ----
  if (use_ws){
    k_syrk128_sig<<<dim3(64,64), 256, 0, stream>>>(Zws, 64, zadj_out);
  } else {
    k_syrk_sig<<<dim3(127,128), 256, 0, stream>>>(Z, 64, zadj_out, 1);
    const float* Zp = Z; float* zp = zadj_out;
    void* args[] = { (void*)&Zp, (void*)&zp };
    hipLaunchCooperativeKernel((const void*)k_zcoop, dim3(1,128), dim3(256,1,1),
                               args, 0, stream);
  }
}

// Round 31
// 700.096 us; speedup vs baseline: 1.0666x; 1.0666x over previous
//
#include <hip/hip_runtime.h>
#include <hip/hip_bf16.h>
#include <hip/hip_cooperative_groups.h>

#define NN 8192
#define NE 131072

namespace cg = cooperative_groups;

typedef __attribute__((ext_vector_type(8))) short bfrag;
typedef __attribute__((ext_vector_type(4))) float f32x4;

__device__ __forceinline__ float sigmoidf_(float x){ return 1.0f/(1.0f + __expf(-x)); }

// ---------------- utility ----------------
__global__ void k_copyf(const float* __restrict__ in, float* __restrict__ out, int n){
  int i = blockIdx.x*blockDim.x + threadIdx.x;
  if (i < n) out[i] = in[i];
}

// ---------------- CSR build (verified) ----------------
__global__ void k_zero(int* __restrict__ p, int n){
  int i = blockIdx.x*blockDim.x + threadIdx.x;
  if (i < n) p[i] = 0;
}
__global__ void k_hist(const int* __restrict__ sidx, int* __restrict__ counts){
  int e = blockIdx.x*blockDim.x + threadIdx.x;
  if (e < NE) atomicAdd(&counts[sidx[e]], 1);
}
__global__ void k_scan(const int* __restrict__ counts, int* __restrict__ row_start,
                       int* __restrict__ cursor){
  __shared__ int part[1024];
  int t = threadIdx.x;
  int base = t*8;
  int local[8]; int s = 0;
  #pragma unroll
  for (int i=0;i<8;i++){ s += counts[base+i]; local[i] = s; }
  part[t] = s;
  __syncthreads();
  for (int off=1; off<1024; off<<=1){
    int v = (t >= off) ? part[t-off] : 0;
    __syncthreads();
    part[t] += v;
    __syncthreads();
  }
  int excl = (t==0) ? 0 : part[t-1];
  int run = excl;
  #pragma unroll
  for (int i=0;i<8;i++){
    cursor[base+i] = run;
    run = excl + local[i];
    row_start[base+i+1] = run;
  }
  if (t==0) row_start[0] = 0;
}
__global__ void k_scatter(const int* __restrict__ sidx, const int* __restrict__ gidx,
                          const float* __restrict__ val, int* __restrict__ cursor,
                          int* __restrict__ gath_s, float* __restrict__ val_s){
  int e = blockIdx.x*blockDim.x + threadIdx.x;
  if (e < NE){
    int r = sidx[e];
    int pos = atomicAdd(&cursor[r], 1);
    gath_s[pos] = gidx[e];
    val_s[pos] = val[e];
  }
}

// ---------------- SpMM (verified) ----------------
__global__ void k_spmm(const int* __restrict__ row_start, const int* __restrict__ gath_s,
                       const float* __restrict__ val_s, const float* __restrict__ S,
                       float* __restrict__ H, int D){
  int r = blockIdx.x;
  int s0 = row_start[r], s1 = row_start[r+1];
  for (int c = threadIdx.x; c < D; c += blockDim.x){
    float acc = 0.f;
    for (int j = s0; j < s1; ++j)
      acc = fmaf(val_s[j], S[(size_t)gath_s[j]*D + c], acc);
    H[(size_t)r*D + c] = acc;
  }
}

// ---------------- SpMM + bf16 hi/lo split epilogue (x_hat, D=512) (verified r30) ----------------
__global__ void k_spmm_split(const int* __restrict__ row_start, const int* __restrict__ gath_s,
                             const float* __restrict__ val_s, const float* __restrict__ S,
                             float* __restrict__ H, short* __restrict__ hi,
                             short* __restrict__ lo, int D){
  int r = blockIdx.x;
  int s0 = row_start[r], s1 = row_start[r+1];
  for (int c = threadIdx.x; c < D; c += blockDim.x){
    float acc = 0.f;
    for (int j = s0; j < s1; ++j)
      acc = fmaf(val_s[j], S[(size_t)gath_s[j]*D + c], acc);
    size_t idx = (size_t)r*D + c;
    H[idx] = acc;
    __hip_bfloat16 h = __float2bfloat16(acc);
    float hf = __bfloat162float(h);
    __hip_bfloat16 l = __float2bfloat16(acc - hf);
    hi[idx] = *(short*)&h;
    lo[idx] = *(short*)&l;
  }
}

// ---------------- fp32 GEMM 64-tile: C = act(A @ B). ACT: 0=none 1=tanh (verified) ----------------
template<int ACT>
__global__ __launch_bounds__(256) void k_gemm64(const float* __restrict__ A,
                                                const float* __restrict__ B,
                                                float* __restrict__ C,
                                                int M, int N, int K){
  __shared__ float As[16][65];
  __shared__ float Bs[16][65];
  int bm = blockIdx.x, bn = blockIdx.y;
  int t = threadIdx.x;
  int tx = t & 15, ty = t >> 4;
  const int rA = t >> 2, kvA = t & 3;
  const int krB = t >> 4, nvB = t & 15;
  float acc[4][4] = {};
  for (int k0 = 0; k0 < K; k0 += 16){
    float4 av = *(const float4*)(A + (size_t)(bm*64 + rA)*K + (k0 + kvA*4));
    float4 bv = *(const float4*)(B + (size_t)(k0 + krB)*N + (bn*64 + nvB*4));
    As[kvA*4+0][rA] = av.x; As[kvA*4+1][rA] = av.y;
    As[kvA*4+2][rA] = av.z; As[kvA*4+3][rA] = av.w;
    Bs[krB][nvB*4+0] = bv.x; Bs[krB][nvB*4+1] = bv.y;
    Bs[krB][nvB*4+2] = bv.z; Bs[krB][nvB*4+3] = bv.w;
    __syncthreads();
    #pragma unroll
    for (int k=0;k<16;k++){
      float a[4], b[4];
      #pragma unroll
      for (int i=0;i<4;i++) a[i] = As[k][ty*4+i];
      #pragma unroll
      for (int j=0;j<4;j++) b[j] = Bs[k][tx*4+j];
      #pragma unroll
      for (int i=0;i<4;i++)
        #pragma unroll
        for (int j=0;j<4;j++)
          acc[i][j] = fmaf(a[i], b[j], acc[i][j]);
    }
    __syncthreads();
  }
  #pragma unroll
  for (int i=0;i<4;i++){
    int rowg = bm*64 + ty*4 + i;
    float4 v;
    v.x = acc[i][0]; v.y = acc[i][1]; v.z = acc[i][2]; v.w = acc[i][3];
    if (ACT == 1){
      v.x = tanhf(v.x); v.y = tanhf(v.y); v.z = tanhf(v.z); v.w = tanhf(v.w);
    }
    *(float4*)(C + (size_t)rowg*N + (bn*64 + tx*4)) = v;
  }
}

// ---------------- split-bf16 MFMA SYRK with sigmoid, symmetric (verified) ----------------
__global__ __launch_bounds__(256) void k_syrk_mfma_sig(const short* __restrict__ Hi,
                                                       const short* __restrict__ Lo,
                                                       int K, float* __restrict__ out){
  int bm = blockIdx.x, bn = blockIdx.y;
  if (bn > bm) return;
  __shared__ short LA[2][128][40];
  __shared__ short LB[2][128][40];
  int t = threadIdx.x;
  int wid = t >> 6, lane = t & 63;
  int r0 = lane & 15;
  int kg = lane >> 4;
  f32x4 acc[2][8];
  #pragma unroll
  for (int i=0;i<2;i++)
    #pragma unroll
    for (int j=0;j<8;j++) acc[i][j] = (f32x4){0.f,0.f,0.f,0.f};

  int tr = t >> 1, th = t & 1;
  const short* gAh = Hi + (size_t)(bm*128 + tr)*K + th*16;
  const short* gAl = Lo + (size_t)(bm*128 + tr)*K + th*16;
  const short* gBh = Hi + (size_t)(bn*128 + tr)*K + th*16;
  const short* gBl = Lo + (size_t)(bn*128 + tr)*K + th*16;

  for (int k0 = 0; k0 < K; k0 += 32){
    *(int4*)&LA[0][tr][th*16] = *(const int4*)(gAh + k0);
    *(int4*)&LA[0][tr][th*16+8] = *(const int4*)(gAh + k0 + 8);
    *(int4*)&LA[1][tr][th*16] = *(const int4*)(gAl + k0);
    *(int4*)&LA[1][tr][th*16+8] = *(const int4*)(gAl + k0 + 8);
    *(int4*)&LB[0][tr][th*16] = *(const int4*)(gBh + k0);
    *(int4*)&LB[0][tr][th*16+8] = *(const int4*)(gBh + k0 + 8);
    *(int4*)&LB[1][tr][th*16] = *(const int4*)(gBl + k0);
    *(int4*)&LB[1][tr][th*16+8] = *(const int4*)(gBl + k0 + 8);
    __syncthreads();
    int ar0 = wid*32 + r0, ar1 = wid*32 + 16 + r0;
    bfrag ah0 = *(bfrag*)&LA[0][ar0][kg*8];
    bfrag ah1 = *(bfrag*)&LA[0][ar1][kg*8];
    bfrag al0 = *(bfrag*)&LA[1][ar0][kg*8];
    bfrag al1 = *(bfrag*)&LA[1][ar1][kg*8];
    #pragma unroll
    for (int j=0;j<8;j++){
      int bc = j*16 + r0;
      bfrag bh = *(bfrag*)&LB[0][bc][kg*8];
      bfrag bl = *(bfrag*)&LB[1][bc][kg*8];
      acc[0][j] = __builtin_amdgcn_mfma_f32_16x16x32_bf16(ah0, bh, acc[0][j], 0,0,0);
      acc[0][j] = __builtin_amdgcn_mfma_f32_16x16x32_bf16(ah0, bl, acc[0][j], 0,0,0);
      acc[0][j] = __builtin_amdgcn_mfma_f32_16x16x32_bf16(al0, bh, acc[0][j], 0,0,0);
      acc[1][j] = __builtin_amdgcn_mfma_f32_16x16x32_bf16(ah1, bh, acc[1][j], 0,0,0);
      acc[1][j] = __builtin_amdgcn_mfma_f32_16x16x32_bf16(ah1, bl, acc[1][j], 0,0,0);
      acc[1][j] = __builtin_amdgcn_mfma_f32_16x16x32_bf16(al1, bh, acc[1][j], 0,0,0);
    }
    __syncthreads();
  }
  #pragma unroll
  for (int i=0;i<2;i++){
    int rb = bm*128 + wid*32 + i*16 + kg*4;
    #pragma unroll
    for (int j=0;j<8;j++){
      int cb = bn*128 + j*16 + r0;
      #pragma unroll
      for (int v=0;v<4;v++){
        float s = sigmoidf_(acc[i][j][v]);
        out[(size_t)(rb+v)*NN + cb] = s;
        if (bm != bn) out[(size_t)cb*NN + (rb+v)] = s;
      }
    }
  }
}

// ---------------- fp32 symmetric 128-tile SYRK (verified; z_adj ws-path) ----------------
__global__ __launch_bounds__(256) void k_syrk128_sig(const float* __restrict__ X, int K,
                                                     float* __restrict__ out){
  int bm = blockIdx.x, bn = blockIdx.y;
  if (bn > bm) return;
  __shared__ float As[16][128];
  __shared__ float Bs[16][128];
  int t = threadIdx.x;
  int tx = t & 15, ty = t >> 4;
  int rL = t >> 1, sL = (t & 1) << 3;
  float acc[4][4][4] = {};
  for (int k0 = 0; k0 < K; k0 += 16){
    const float* pa = X + (size_t)(bm*128 + rL)*K + (k0 + sL);
    const float* pb = X + (size_t)(bn*128 + rL)*K + (k0 + sL);
    float4 a0 = *(const float4*)pa, a1 = *(const float4*)(pa+4);
    float4 b0 = *(const float4*)pb, b1 = *(const float4*)(pb+4);
    As[sL+0][rL]=a0.x; As[sL+1][rL]=a0.y; As[sL+2][rL]=a0.z; As[sL+3][rL]=a0.w;
    As[sL+4][rL]=a1.x; As[sL+5][rL]=a1.y; As[sL+6][rL]=a1.z; As[sL+7][rL]=a1.w;
    Bs[sL+0][rL]=b0.x; Bs[sL+1][rL]=b0.y; Bs[sL+2][rL]=b0.z; Bs[sL+3][rL]=b0.w;
    Bs[sL+4][rL]=b1.x; Bs[sL+5][rL]=b1.y; Bs[sL+6][rL]=b1.z; Bs[sL+7][rL]=b1.w;
    __syncthreads();
    #pragma unroll
    for (int k=0;k<16;k++){
      float4 a0v = *(const float4*)&As[k][ty*4];
      float4 a1v = *(const float4*)&As[k][64 + ty*4];
      float4 b0v = *(const float4*)&Bs[k][tx*4];
      float4 b1v = *(const float4*)&Bs[k][64 + tx*4];
      float ar[8] = {a0v.x,a0v.y,a0v.z,a0v.w, a1v.x,a1v.y,a1v.z,a1v.w};
      float br[8] = {b0v.x,b0v.y,b0v.z,b0v.w, b1v.x,b1v.y,b1v.z,b1v.w};
      #pragma unroll
      for (int sub=0; sub<4; ++sub){
        int ai = (sub>>1)<<2, bj = (sub&1)<<2;
        #pragma unroll
        for (int i=0;i<4;i++)
          #pragma unroll
          for (int j=0;j<4;j++)
            acc[sub][i][j] = fmaf(ar[ai+i], br[bj+j], acc[sub][i][j]);
      }
    }
    __syncthreads();
  }
  #pragma unroll
  for (int sub=0; sub<4; ++sub)
    #pragma unroll
    for (int i=0;i<4;i++)
      #pragma unroll
      for (int j=0;j<4;j++)
        acc[sub][i][j] = sigmoidf_(acc[sub][i][j]);
  #pragma unroll
  for (int sub=0; sub<4; ++sub){
    int rb = bm*128 + ((sub>>1)<<6) + ty*4;
    int cb = bn*128 + ((sub&1)<<6) + tx*4;
    #pragma unroll
    for (int i=0;i<4;i++){
      float4 v;
      v.x = acc[sub][i][0]; v.y = acc[sub][i][1];
      v.z = acc[sub][i][2]; v.w = acc[sub][i][3];
      *(float4*)(out + (size_t)(rb+i)*NN + cb) = v;
    }
    if (bm != bn){
      #pragma unroll
      for (int j=0;j<4;j++){
        float4 w;
        w.x = acc[sub][0][j]; w.y = acc[sub][1][j];
        w.z = acc[sub][2][j]; w.w = acc[sub][3][j];
        *(float4*)(out + (size_t)(cb+j)*NN + rb) = w;
      }
    }
  }
}

// ---------------- old 64-tile sigmoid SYRK (verified; no-ws z_adj path) ----------------
__global__ __launch_bounds__(256) void k_syrk_sig(const float* __restrict__ X, int K,
                                                  float* __restrict__ out, int bm0){
  __shared__ float As[16][65];
  __shared__ float Bs[16][65];
  int bm = blockIdx.x + bm0, bn = blockIdx.y;
  int t = threadIdx.x;
  int tx = t & 15, ty = t >> 4;
  const int rL = t >> 2, kvL = t & 3;
  float acc[4][4] = {};
  for (int k0 = 0; k0 < K; k0 += 16){
    float4 av = *(const float4*)(X + (size_t)(bm*64 + rL)*K + (k0 + kvL*4));
    float4 bv = *(const float4*)(X + (size_t)(bn*64 + rL)*K + (k0 + kvL*4));
    As[kvL*4+0][rL] = av.x; As[kvL*4+1][rL] = av.y;
    As[kvL*4+2][rL] = av.z; As[kvL*4+3][rL] = av.w;
    Bs[kvL*4+0][rL] = bv.x; Bs[kvL*4+1][rL] = bv.y;
    Bs[kvL*4+2][rL] = bv.z; Bs[kvL*4+3][rL] = bv.w;
    __syncthreads();
    #pragma unroll
    for (int k=0;k<16;k++){
      float a[4], b[4];
      #pragma unroll
      for (int i=0;i<4;i++) a[i] = As[k][ty*4+i];
      #pragma unroll
      for (int j=0;j<4;j++) b[j] = Bs[k][tx*4+j];
      #pragma unroll
      for (int i=0;i<4;i++)
        #pragma unroll
        for (int j=0;j<4;j++)
          acc[i][j] = fmaf(a[i], b[j], acc[i][j]);
    }
    __syncthreads();
  }
  #pragma unroll
  for (int i=0;i<4;i++){
    int rowg = bm*64 + ty*4 + i;
    float4 v;
    v.x = sigmoidf_(acc[i][0]); v.y = sigmoidf_(acc[i][1]);
    v.z = sigmoidf_(acc[i][2]); v.w = sigmoidf_(acc[i][3]);
    *(float4*)(out + (size_t)rowg*NN + (bn*64 + tx*4)) = v;
  }
}

// ---------------- cooperative fallback: z_adj rows 0..63 (verified) ----------------
__global__ __launch_bounds__(256) void k_zcoop(const float* __restrict__ Z,
                                               float* __restrict__ zadj){
  __shared__ float Za[64][65];
  __shared__ float Zb[64][65];
  int bm = blockIdx.x;
  int bn = blockIdx.y;
  int t = threadIdx.x;
  #pragma unroll
  for (int q=0;q<4;q++){
    int lin = q*256 + t;
    int r  = lin >> 4;
    int kq = lin & 15;
    float4 a = *(const float4*)(Z + (size_t)(bm*64 + r)*64 + kq*4);
    float4 b = *(const float4*)(Z + (size_t)(bn*64 + r)*64 + kq*4);
    Za[kq*4+0][r] = a.x; Za[kq*4+1][r] = a.y; Za[kq*4+2][r] = a.z; Za[kq*4+3][r] = a.w;
    Zb[kq*4+0][r] = b.x; Zb[kq*4+1][r] = b.y; Zb[kq*4+2][r] = b.z; Zb[kq*4+3][r] = b.w;
  }
  cg::this_grid().sync();
  int tx = t & 15, ty = t >> 4;
  float acc[4][4] = {};
  #pragma unroll 16
  for (int k=0;k<64;k++){
    float a[4], b[4];
    #pragma unroll
    for (int i=0;i<4;i++) a[i] = Za[k][ty*4+i];
    #pragma unroll
    for (int j=0;j<4;j++) b[j] = Zb[k][tx*4+j];
    #pragma unroll
    for (int i=0;i<4;i++)
      #pragma unroll
      for (int j=0;j<4;j++)
        acc[i][j] = fmaf(a[i], b[j], acc[i][j]);
  }
  #pragma unroll
  for (int i=0;i<4;i++){
    int rowg = bm*64 + ty*4 + i;
    float4 v;
    v.x = sigmoidf_(acc[i][0]); v.y = sigmoidf_(acc[i][1]);
    v.z = sigmoidf_(acc[i][2]); v.w = sigmoidf_(acc[i][3]);
    *(float4*)(zadj + (size_t)rowg*NN + (bn*64 + tx*4)) = v;
  }
}

extern "C" void kernel_launch(void* const* d_in, const int* in_sizes, int n_in,
                              void* d_out, int out_size, void* d_ws, size_t ws_size,
                              hipStream_t stream){
  (void)in_sizes; (void)n_in; (void)out_size;
  const float* x       = (const float*)d_in[0];
  const int*   adj_row = (const int*)d_in[1];
  const int*   adj_col = (const int*)d_in[2];
  const float* adj_val = (const float*)d_in[3];
  const float* W1 = (const float*)d_in[4];
  const float* W2 = (const float*)d_in[5];
  const float* W3 = (const float*)d_in[6];
  const float* W4 = (const float*)d_in[7];
  const float* W5 = (const float*)d_in[8];
  const float* W6 = (const float*)d_in[9];

  float* out      = (float*)d_out;
  float* zx_out   = out;                       // [8192,64]    f32 (pass)
  float* zadj_out = out + 524288;              // [8192,8192]  f32 (pass)
  float* xhat_out = out + 67633152;            // [8192,512]   f32 (pass)
  float* adj_out  = out + 71827456;            // [8192,8192]  f32 (pass)

  const size_t MiB = (size_t)1 << 20;
  char* R1 = (char*)zadj_out;
  float* Z   = (float*)(R1 + 0*MiB);
  float* S   = (float*)(R1 + 4*MiB);
  float* H   = (float*)(R1 + 24*MiB);
  short* XHi = (short*)(R1 + 34*MiB);          // [8192][512] bf16 hi
  short* XLo = (short*)(R1 + 43*MiB);          // [8192][512] bf16 lo
  int*   counts    = (int*)(R1 + 52*MiB);
  int*   row_start = counts + NN;
  int*   cursor    = row_start + NN + 1;
  int*   gath_s    = cursor + NN;
  float* val_s     = (float*)(gath_s + NE);
  float* Zws = (float*)d_ws;
  const bool use_ws = (ws_size >= 2*MiB);

  // ---- CSR build (VERIFIED) ----
  k_zero<<<NN/256, 256, 0, stream>>>(counts, NN);
  k_hist<<<NE/256, 256, 0, stream>>>(adj_row, counts);
  k_scan<<<1, 1024, 0, stream>>>(counts, row_start, cursor);
  k_scatter<<<NE/256, 256, 0, stream>>>(adj_row, adj_col, adj_val, cursor, gath_s, val_s);

  // ---- encoder: tanh, tanh, linear pre-agg (gemm64 = best measured config) ----
  k_gemm64<1><<<dim3(128,4), 256, 0, stream>>>(x, W1, S, NN, 256, 512);
  k_spmm<<<NN, 256, 0, stream>>>(row_start, gath_s, val_s, S, H, 256);
  k_gemm64<1><<<dim3(128,2), 256, 0, stream>>>(H, W2, S, NN, 128, 256);
  k_spmm<<<NN, 128, 0, stream>>>(row_start, gath_s, val_s, S, H, 128);
  k_gemm64<0><<<dim3(128,1), 256, 0, stream>>>(H, W3, S, NN, 64, 128);
  k_spmm<<<NN, 64, 0, stream>>>(row_start, gath_s, val_s, S, Z, 64);
  if (use_ws) k_copyf<<<2048, 256, 0, stream>>>(Z, Zws, NN*64);
  k_copyf<<<2048, 256, 0, stream>>>(Z, zx_out, NN*64);           // z_x FINAL

  // ---- decoder: tanh x3 pre-agg; last spmm fuses bf16 split ----
  k_gemm64<1><<<dim3(128,2), 256, 0, stream>>>(Z, W4, S, NN, 128, 64);
  k_spmm<<<NN, 128, 0, stream>>>(row_start, gath_s, val_s, S, H, 128);
  k_gemm64<1><<<dim3(128,4), 256, 0, stream>>>(H, W5, S, NN, 256, 128);
  k_spmm<<<NN, 256, 0, stream>>>(row_start, gath_s, val_s, S, H, 256);
  k_gemm64<1><<<dim3(128,8), 256, 0, stream>>>(H, W6, S, NN, 512, 256);
  k_spmm_split<<<NN, 256, 0, stream>>>(row_start, gath_s, val_s, S, xhat_out,
                                       XHi, XLo, 512);           // x_hat FINAL + split

  // ---- adj_hat: split-bf16 MFMA syrk (verified) ----
  k_syrk_mfma_sig<<<dim3(64,64), 256, 0, stream>>>(XHi, XLo, 512, adj_out);   // adj FINAL

  // ---- z_adj LAST ----
  if (use_ws){
    k_syrk128_sig<<<dim3(64,64), 256, 0, stream>>>(Zws, 64, zadj_out);
  } else {
    k_syrk_sig<<<dim3(127,128), 256, 0, stream>>>(Z, 64, zadj_out, 1);
    const float* Zp = Z; float* zp = zadj_out;
    void* args[] = { (void*)&Zp, (void*)&zp };
    hipLaunchCooperativeKernel((const void*)k_zcoop, dim3(1,128), dim3(256,1,1),
                               args, 0, stream);
  }
}